// Round 16
// baseline (91.586 us; speedup 1.0000x reference)
//
#include <hip/hip_runtime.h>
#include <hip/hip_bf16.h>

// Flash attention fwd, causal + key-padding, B=4 S=4096 D=64, fp32 in/out.
// Round 16: BARRIER-FREE 1-wave blocks. Rounds 12/15 showed the 4-wave
// block runs lock-step (barrier-coupled): all waves stall together, ~33%
// busy, 21% occupancy regardless of LDS/VGPR/partition changes. Here each
// 64-thread block is ONE wave owning 32 q rows + private K/V LDS tiles
// (16.4KB -> ~9 independent waves/CU, zero __syncthreads). Staging is
// in-lane (V transposed within the lane's own 4x4 block, no shfl); the
// LDS image (FK/FV swizzles) is byte-identical to round 15, so the whole
// compute section is unchanged. Merge kernel unchanged in math (32-row
// slots). Uniform CL-tile split-KV + heavy-first retained.

#define S_LEN 4096
#define D_DIM 64
#define NBATCH 4
#define KVBLK 64
#define NQW 128                     // 32-row q-blocks per batch
#define SLOT_B 4352                 // 4K bf16 O (32x64) + 128B m + 128B l

typedef __attribute__((ext_vector_type(16))) float f32x16;
typedef __attribute__((ext_vector_type(4))) float f32x4;
typedef __attribute__((ext_vector_type(8))) short s16x8;
typedef __attribute__((ext_vector_type(4))) short s16x4;
typedef __attribute__((ext_vector_type(2))) unsigned int u32x2;

#define FK(n) ((((n) ^ ((n) >> 3)) & 7) << 4)                    // K swizzle
#define FV(d) (((((d) & 7) << 4)) ^ ((((d) >> 3) & 1) << 3))     // V^T swizzle

__device__ __forceinline__ unsigned short f2bfu(float f) {
  return __builtin_bit_cast(unsigned short, __float2bfloat16(f));
}
__device__ __forceinline__ unsigned pk2(float a, float b) {
  return (unsigned)f2bfu(a) | ((unsigned)f2bfu(b) << 16);
}
__device__ __forceinline__ float bf2f(short s) {
  return __builtin_bit_cast(float, ((unsigned)(unsigned short)s) << 16);
}

__global__ __launch_bounds__(64, 3) void fattn_partial(
    const float* __restrict__ Qg, const float* __restrict__ Kg,
    const float* __restrict__ Vg, const unsigned char* __restrict__ Pad,
    char* __restrict__ Ws, int CL, int TOTC)
{
  // Uniform partition over (qb, ci): nt(qb)=ceil((qb+1)/2) tiles, chunks of
  // CL. Heavy-first: u descending in enumeration order.
  const int wid = blockIdx.x;
  const int b   = wid & 3;
  const int u   = TOTC - 1 - (wid >> 2);
  int qb = 0, ci = 0;
  {
    int uu = u, q = 0;
    while (true) {
      const int nt_  = (q + 2) >> 1;
      const int nch = (nt_ + CL - 1) / CL;
      if (uu < nch) { ci = uu; break; }
      uu -= nch; ++q;
    }
    qb = q;
  }
  const int qw0 = 32 * qb;
  const int nt  = (qb + 2) >> 1;
  const int t0  = ci * CL;
  const int t1  = (t0 + CL < nt) ? (t0 + CL) : nt;

  const int l   = threadIdx.x;       // single wave
  const int ql  = l & 31;
  const int hi  = l >> 5;
  const int qa  = qw0 + ql;

  // staging roles (this wave covers the whole 64x64 tile alone)
  const int krow = l >> 2;           // K row group base (rows krow+16i)
  const int kd0  = (l & 3) << 4;     // K d-window [kd0, kd0+16)
  const int vn0  = (l & 15) << 2;    // V n-window [vn0, vn0+4)
  const int vdg  = l >> 4;           // V d-group base (d0 = 4*(vdg+4i))

  __shared__ short Ksh[KVBLK * D_DIM];    // [n][d] bf16, FK-swizzled
  __shared__ short Vtsh[D_DIM * KVBLK];   // [d][n] bf16 (V^T), FV-swizzled

  const size_t bS = (size_t)b * S_LEN;
  const unsigned char* PadB = Pad + bS;

  // ---- wave-level padding flag for this chunk's key range ----
  bool anyPad;
  {
    const int nk = (t1 - t0) * KVBLK;     // <= 512, multiple of 64
    bool nz = false;
    if (8 * l < nk) {
      const unsigned* pp = (const unsigned*)(PadB + t0 * KVBLK + 8 * l);
      nz = (pp[0] | pp[1]) != 0u;
    }
    anyPad = (__ballot(nz) != 0ull);
  }

  // ---- Q fragments (B-operand), pre-scaled by 1/8 ----
  s16x8 qf[4];
  {
    const float* qp = Qg + (bS + qa) * D_DIM + 8 * hi;
    #pragma unroll
    for (int dc = 0; dc < 4; ++dc)
      #pragma unroll
      for (int j = 0; j < 8; ++j)
        qf[dc][j] = (short)f2bfu(qp[16 * dc + j] * 0.125f);
  }

  f32x16 acc[2];
  #pragma unroll
  for (int dt = 0; dt < 2; ++dt)
    #pragma unroll
    for (int i = 0; i < 16; ++i) acc[dt][i] = 0.f;
  float mrow = -INFINITY;
  float lrow = 0.f;

  for (int t = t0; t < t1; ++t) {
    const int kv0 = t * KVBLK;

    // ---- stage K: 4 rows x 16-float window per lane ----
    #pragma unroll
    for (int i = 0; i < 4; ++i) {
      const int nk = krow + 16 * i;
      const float* kp = Kg + (bS + kv0 + nk) * D_DIM + kd0;
      char* rowp = (char*)Ksh + nk * 128;
      #pragma unroll
      for (int j = 0; j < 4; ++j) {
        const float4 kx = *(const float4*)(kp + 4 * j);
        u32x2 kb;
        kb[0] = pk2(kx.x, kx.y); kb[1] = pk2(kx.z, kx.w);
        *(u32x2*)(rowp + ((2 * (kd0 + 4 * j)) ^ FK(nk))) = kb;
      }
    }
    // ---- stage V: 4 in-lane 4x4 transposes per lane ----
    #pragma unroll
    for (int i = 0; i < 4; ++i) {
      const int d0v = 4 * (vdg + 4 * i);
      const float* vp = Vg + (bS + kv0 + vn0) * D_DIM + d0v;
      const float4 r0 = *(const float4*)(vp);
      const float4 r1 = *(const float4*)(vp + D_DIM);
      const float4 r2 = *(const float4*)(vp + 2 * D_DIM);
      const float4 r3 = *(const float4*)(vp + 3 * D_DIM);
      const float* f0 = (const float*)&r0;
      const float* f1 = (const float*)&r1;
      const float* f2 = (const float*)&r2;
      const float* f3 = (const float*)&r3;
      #pragma unroll
      for (int j = 0; j < 4; ++j) {
        const int d = d0v + j;
        u32x2 p;
        p[0] = pk2(f0[j], f1[j]); p[1] = pk2(f2[j], f3[j]);
        *(u32x2*)((char*)Vtsh + d * 128 + ((2 * vn0) ^ FV(d))) = p;
      }
    }
    // no barrier: same-wave DS ops execute in order; lgkmcnt guards data.

    // ---- S^T = mfma(A=K, B=Q): col=lane&31=q, row=k ----
    f32x16 sv[2];
    __builtin_amdgcn_s_setprio(1);
    #pragma unroll
    for (int kt = 0; kt < 2; ++kt) {
      f32x16 a;
      #pragma unroll
      for (int i = 0; i < 16; ++i) a[i] = 0.f;
      #pragma unroll
      for (int dc = 0; dc < 4; ++dc) {
        const int nr = 32 * kt + ql;
        const s16x8 kf = *(const s16x8*)((char*)Ksh + nr * 128 +
                                         ((32 * dc + 16 * hi) ^ FK(nr)));
        a = __builtin_amdgcn_mfma_f32_32x32x16_bf16(kf, qf[dc], a, 0, 0, 0);
      }
      sv[kt] = a;
    }
    __builtin_amdgcn_s_setprio(0);

    // ---- padding (rare path) ----
    if (anyPad) {
      #pragma unroll
      for (int kt = 0; kt < 2; ++kt)
        #pragma unroll
        for (int r1 = 0; r1 < 4; ++r1) {
          const unsigned pd =
              *(const unsigned*)(PadB + kv0 + 32 * kt + 8 * r1 + 4 * hi);
          #pragma unroll
          for (int r0 = 0; r0 < 4; ++r0)
            if ((pd >> (8 * r0)) & 0xFFu) sv[kt][4 * r1 + r0] = -1e30f;
        }
    }
    // ---- causal mask (diagonal band only): k = kv0+32kt+8r1+4hi+r0 ----
    #pragma unroll
    for (int kt = 0; kt < 2; ++kt) {
      const int kvt = kv0 + 32 * kt;
      if (kvt + 31 > qw0) {
        #pragma unroll
        for (int r1 = 0; r1 < 4; ++r1)
          #pragma unroll
          for (int r0 = 0; r0 < 4; ++r0)
            if (kvt + 8 * r1 + 4 * hi + r0 > qa) sv[kt][4 * r1 + r0] = -1e30f;
      }
    }

    // ---- in-register online softmax: TREE max, 4-way sum ----
    f32x16 mx;
    #pragma unroll
    for (int i = 0; i < 16; ++i) mx[i] = fmaxf(sv[0][i], sv[1][i]);
    f32x4 m4;
    #pragma unroll
    for (int i = 0; i < 4; ++i)
      m4[i] = fmaxf(fmaxf(mx[i], mx[i + 4]), fmaxf(mx[i + 8], mx[i + 12]));
    float vm = fmaxf(fmaxf(m4[0], m4[1]), fmaxf(m4[2], m4[3]));
    vm = fmaxf(vm, __shfl_xor(vm, 32));           // merge across hi halves
    const float mn   = fmaxf(mrow, vm);
    const float corr = __expf(mrow - mn);
    mrow = mn;
    lrow *= corr;
    #pragma unroll
    for (int dt = 0; dt < 2; ++dt)
      #pragma unroll
      for (int i = 0; i < 16; ++i) acc[dt][i] *= corr;

    float rs0 = 0.f, rs1 = 0.f, rs2 = 0.f, rs3 = 0.f;
    #pragma unroll
    for (int kt = 0; kt < 2; ++kt)
      #pragma unroll
      for (int i4 = 0; i4 < 16; i4 += 4) {
        const float p0 = __expf(sv[kt][i4 + 0] - mn);
        const float p1 = __expf(sv[kt][i4 + 1] - mn);
        const float p2 = __expf(sv[kt][i4 + 2] - mn);
        const float p3 = __expf(sv[kt][i4 + 3] - mn);
        sv[kt][i4 + 0] = p0; sv[kt][i4 + 1] = p1;
        sv[kt][i4 + 2] = p2; sv[kt][i4 + 3] = p3;
        rs0 += p0; rs1 += p1; rs2 += p2; rs3 += p3;
      }
    lrow += (rs0 + rs1) + (rs2 + rs3);            // own half-sum only

    // ---- O^T += mfma(A=V^T, B=P) ----
    // P B-frag in C/D-native k-order: elem j <-> k = 4hi+(j&3)+8*(j>>2).
    // V^T A-frag reads the SAME element->k map (two 8B LDS reads).
    __builtin_amdgcn_s_setprio(1);
    #pragma unroll
    for (int sk = 0; sk < 4; ++sk) {
      const int kt = sk >> 1, rb = 8 * (sk & 1);
      union { unsigned u[4]; s16x8 v; } pb;
      pb.u[0] = pk2(sv[kt][rb + 0], sv[kt][rb + 1]);
      pb.u[1] = pk2(sv[kt][rb + 2], sv[kt][rb + 3]);
      pb.u[2] = pk2(sv[kt][rb + 4], sv[kt][rb + 5]);
      pb.u[3] = pk2(sv[kt][rb + 6], sv[kt][rb + 7]);
      #pragma unroll
      for (int dt = 0; dt < 2; ++dt) {
        const int dr = 32 * dt + ql;
        const char* vrow = (char*)Vtsh + dr * 128;
        const s16x4 v0 = *(const s16x4*)(vrow + ((32 * sk + 8 * hi) ^ FV(dr)));
        const s16x4 v1 = *(const s16x4*)(vrow + ((32 * sk + 16 + 8 * hi) ^ FV(dr)));
        s16x8 vf;
        vf[0] = v0[0]; vf[1] = v0[1]; vf[2] = v0[2]; vf[3] = v0[3];
        vf[4] = v1[0]; vf[5] = v1[1]; vf[6] = v1[2]; vf[7] = v1[3];
        acc[dt] = __builtin_amdgcn_mfma_f32_32x32x16_bf16(vf, pb.v, acc[dt], 0, 0, 0);
      }
    }
    __builtin_amdgcn_s_setprio(0);
  }

  // ---- epilogue: merge l across hi halves; write bf16 partial slot ----
  const float lt = lrow + __shfl_xor(lrow, 32);

  char* slot = Ws + ((size_t)b * TOTC + u) * SLOT_B;
  #pragma unroll
  for (int dt = 0; dt < 2; ++dt)
    #pragma unroll
    for (int r1 = 0; r1 < 4; ++r1) {
      u32x2 p;
      p[0] = pk2(acc[dt][4 * r1 + 0], acc[dt][4 * r1 + 1]);
      p[1] = pk2(acc[dt][4 * r1 + 2], acc[dt][4 * r1 + 3]);
      *(u32x2*)(slot + ql * 128 + (32 * dt + 8 * r1 + 4 * hi) * 2) = p;
    }
  if (hi == 0) {
    ((float*)(slot + 4096))[ql]       = mrow;
    ((float*)(slot + 4096 + 128))[ql] = lt;
  }
}

__global__ __launch_bounds__(256, 8) void fattn_merge(
    const char* __restrict__ Ws, float* __restrict__ Og, int CL, int TOTC)
{
  const int blk = blockIdx.x;            // 512 = 4 batches * 128 qb
  const int b   = blk >> 7;
  const int qb  = blk & 127;
  const int tid = threadIdx.x;
  const int row = tid >> 3;              // q row within 32-block
  const int d0  = (tid & 7) * 8;         // 8 d-elems per thread

  const int nt     = (qb + 2) >> 1;
  const int nvalid = (nt + CL - 1) / CL;
  int pre = 0;
  for (int q = 0; q < qb; ++q) pre += (((q + 2) >> 1) + CL - 1) / CL;

  const char* base = Ws + ((size_t)b * TOTC + pre) * SLOT_B;

  float mstar = -INFINITY;
  for (int ci = 0; ci < nvalid; ++ci)
    mstar = fmaxf(mstar, ((const float*)(base + (size_t)ci * SLOT_B + 4096))[row]);

  float lsum = 0.f;
  float o[8];
  #pragma unroll
  for (int k = 0; k < 8; ++k) o[k] = 0.f;

  for (int ci = 0; ci < nvalid; ++ci) {
    const char* slot = base + (size_t)ci * SLOT_B;
    const float wgt = __expf(((const float*)(slot + 4096))[row] - mstar);
    lsum += wgt * ((const float*)(slot + 4096 + 128))[row];
    const s16x8 ov = *(const s16x8*)(slot + row * 128 + d0 * 2);
    #pragma unroll
    for (int k = 0; k < 8; ++k) o[k] += wgt * bf2f(ov[k]);
  }

  const float inv = 1.0f / lsum;
  float* op = Og + ((size_t)(b * S_LEN + 32 * qb + row)) * D_DIM + d0;
  f32x4 o0, o1;
  #pragma unroll
  for (int k = 0; k < 4; ++k) { o0[k] = o[k] * inv; o1[k] = o[4 + k] * inv; }
  *(f32x4*)(op) = o0;
  *(f32x4*)(op + 4) = o1;
}

extern "C" void kernel_launch(void* const* d_in, const int* in_sizes, int n_in,
                              void* d_out, int out_size, void* d_ws, size_t ws_size,
                              hipStream_t stream) {
  const float* Q = (const float*)d_in[0];
  const float* K = (const float*)d_in[1];
  const float* V = (const float*)d_in[2];
  const unsigned char* P = (const unsigned char*)d_in[3];
  float* O  = (float*)d_out;
  char*  Ws = (char*)d_ws;

  // chunk length CL=4 if the slot pool fits, else 8
  int CL = 4;
  int TOTC = 0;
  for (int q = 0; q < NQW; ++q) TOTC += (((q + 2) >> 1) + CL - 1) / CL;  // 1088
  if (ws_size < (size_t)NBATCH * TOTC * SLOT_B) {
    CL = 8;
    TOTC = 0;
    for (int q = 0; q < NQW; ++q) TOTC += (((q + 2) >> 1) + CL - 1) / CL; // 576
  }

  hipLaunchKernelGGL(fattn_partial, dim3(NBATCH * TOTC), dim3(64), 0, stream,
                     Q, K, V, P, Ws, CL, TOTC);
  hipLaunchKernelGGL(fattn_merge, dim3(NBATCH * NQW), dim3(256), 0, stream,
                     Ws, O, CL, TOTC);
}

// Round 17
// 56.054 us; speedup vs baseline: 1.6339x; 1.6339x over previous
//
#include <hip/hip_runtime.h>
#include <hip/hip_bf16.h>

// Flash attention fwd, causal + key-padding, B=4 S=4096 D=64, fp32 in/out.
// Round 17: round-15 green base (two-kernel, 4-wave blocks, uniform CL-tile
// partition, single-buffer LDS, bf16-at-load staging) with:
//  (a) in-lane V 4x4 transpose staging (256 threads x one 4x4 block each;
//      same amortization as round 15, deletes 8 shfl + ~24 ALU/thread/tile;
//      LDS image byte-identical) — round 16's mistake was 1-wave blocks
//      (4x redundant staging), not the in-lane transpose itself;
//  (b) kt-sequential online softmax: two 32-k online steps per tile, sv
//      shrinks 32->16 VGPRs targeting <=128 total/wave -> 4 waves/SIMD
//      (reg-demand reduction instead of round 10's forced-bound spill).

#define S_LEN 4096
#define D_DIM 64
#define NBATCH 4
#define QBLK 128
#define KVBLK 64
#define NQB (S_LEN / QBLK)          // 32 q-blocks per batch
#define SLOT_B 17408                // 16K bf16 O + 1K fp32 m/l

typedef __attribute__((ext_vector_type(16))) float f32x16;
typedef __attribute__((ext_vector_type(4))) float f32x4;
typedef __attribute__((ext_vector_type(8))) short s16x8;
typedef __attribute__((ext_vector_type(4))) short s16x4;
typedef __attribute__((ext_vector_type(2))) unsigned int u32x2;

#define FK(n) ((((n) ^ ((n) >> 3)) & 7) << 4)                    // K swizzle
#define FV(d) (((((d) & 7) << 4)) ^ ((((d) >> 3) & 1) << 3))     // V^T swizzle

__device__ __forceinline__ unsigned short f2bfu(float f) {
  return __builtin_bit_cast(unsigned short, __float2bfloat16(f));
}
__device__ __forceinline__ unsigned pk2(float a, float b) {
  return (unsigned)f2bfu(a) | ((unsigned)f2bfu(b) << 16);
}
__device__ __forceinline__ float bf2f(short s) {
  return __builtin_bit_cast(float, ((unsigned)(unsigned short)s) << 16);
}

__global__ __launch_bounds__(256, 3) void fattn_partial(
    const float* __restrict__ Qg, const float* __restrict__ Kg,
    const float* __restrict__ Vg, const unsigned char* __restrict__ Pad,
    char* __restrict__ Ws, int CL, int TOTC)
{
  // Uniform partition: enumeration index u -> (Qb, ci); heavy-first.
  const int wid = blockIdx.x;
  const int b   = wid & 3;
  const int u   = TOTC - 1 - (wid >> 2);
  int Qb = 0, ci = 0;
  {
    int uu = u, q = 0;
    while (true) {
      const int nch = (2 * q + 2 + CL - 1) / CL;
      if (uu < nch) { ci = uu; break; }
      uu -= nch; ++q;
    }
    Qb = q;
  }
  const int q0  = Qb * QBLK;
  const int ntt = 2 * Qb + 2;
  const int t0  = ci * CL;
  const int t1  = (t0 + CL < ntt) ? (t0 + CL) : ntt;

  const int tid = threadIdx.x;
  const int w   = tid >> 6;          // wave 0..3 -> q rows [q0+32w, q0+32w+32)
  const int l   = tid & 63;
  const int ql  = l & 31;
  const int hi  = l >> 5;
  const int qw0 = q0 + 32 * w;
  const int qa  = qw0 + ql;

  // K staging roles (64 rows x 16-float windows over 256 threads)
  const int sq  = l & 3;
  const int sm  = (l >> 2) & 3;
  const int sc2 = l >> 4;
  const int snb = 4 * w + 16 * sc2;  // n-chunk base (multiple of 4)
  // V staging roles: one 4x4 block per thread (in-lane transpose)
  const int vn0 = (tid & 15) << 2;   // V rows [vn0, vn0+4)
  const int vd0 = (tid >> 4) << 2;   // V cols [vd0, vd0+4)

  __shared__ short Ksh[KVBLK * D_DIM];    // [n][d] bf16, FK-swizzled
  __shared__ short Vtsh[D_DIM * KVBLK];   // [d][n] bf16 (V^T), FV-swizzled
  __shared__ int anyPadSh;

  const size_t bS = (size_t)b * S_LEN;
  const unsigned char* PadB = Pad + bS;

  // ---- prologue: block-wide padding flag for this chunk's key range ----
  if (tid == 0) anyPadSh = 0;
  __syncthreads();
  {
    const int nk  = (t1 - t0) * KVBLK;      // <= 512
    const int idx = 2 * tid;
    if (idx < nk) {
      const unsigned char* pp = PadB + t0 * KVBLK + idx;
      const bool nz = pp[0] || ((idx + 1 < nk) ? pp[1] : (unsigned char)0);
      if (nz) anyPadSh = 1;                 // benign same-value race
    }
  }

  // ---- Q fragments (B-operand), pre-scaled by 1/8 ----
  s16x8 qf[4];
  {
    const float* qp = Qg + (bS + qa) * D_DIM + 8 * hi;
    #pragma unroll
    for (int dc = 0; dc < 4; ++dc)
      #pragma unroll
      for (int j = 0; j < 8; ++j)
        qf[dc][j] = (short)f2bfu(qp[16 * dc + j] * 0.125f);
  }

  f32x16 acc[2];
  #pragma unroll
  for (int dt = 0; dt < 2; ++dt)
    #pragma unroll
    for (int i = 0; i < 16; ++i) acc[dt][i] = 0.f;
  float mrow = -INFINITY;
  float lrow = 0.f;

  u32x2 kpb[4], vpb[4];   // bf16-packed prefetch; vpb already transposed

#define LOAD_KV(T) do {                                                      \
    const int kv0_ = (T) * KVBLK;                                            \
    _Pragma("unroll")                                                        \
    for (int s_ = 0; s_ < 4; ++s_) {                                         \
      const size_t go_ =                                                     \
          (bS + kv0_ + snb + sq) * D_DIM + 16 * s_ + 4 * sm;                 \
      const float4 kx = *(const float4*)(Kg + go_);                          \
      kpb[s_][0] = pk2(kx.x, kx.y); kpb[s_][1] = pk2(kx.z, kx.w);            \
    }                                                                        \
    const float* vp_ = Vg + (bS + kv0_ + vn0) * D_DIM + vd0;                 \
    const float4 r0 = *(const float4*)(vp_);                                 \
    const float4 r1 = *(const float4*)(vp_ + D_DIM);                         \
    const float4 r2 = *(const float4*)(vp_ + 2 * D_DIM);                     \
    const float4 r3 = *(const float4*)(vp_ + 3 * D_DIM);                     \
    const float* f0 = (const float*)&r0; const float* f1 = (const float*)&r1;\
    const float* f2 = (const float*)&r2; const float* f3 = (const float*)&r3;\
    _Pragma("unroll")                                                        \
    for (int j_ = 0; j_ < 4; ++j_) {                                         \
      vpb[j_][0] = pk2(f0[j_], f1[j_]);                                      \
      vpb[j_][1] = pk2(f2[j_], f3[j_]);                                      \
    }                                                                        \
  } while (0)

#define STAGE() do {                                                         \
    _Pragma("unroll")                                                        \
    for (int s_ = 0; s_ < 4; ++s_) {                                         \
      const int d0_ = 16 * s_ + 4 * sm; const int nk_ = snb + sq;            \
      *(u32x2*)((char*)&Ksh[0] + nk_ * 128 + ((2 * d0_) ^ FK(nk_))) =        \
          kpb[s_];                                                           \
      const int dv_ = vd0 + s_;                                              \
      *(u32x2*)((char*)&Vtsh[0] + dv_ * 128 + ((2 * vn0) ^ FV(dv_))) =       \
          vpb[s_];                                                           \
    }                                                                        \
  } while (0)

  LOAD_KV(t0);

  for (int t = t0; t < t1; ++t) {
    STAGE();                          // write prefetched tile to LDS
    __syncthreads();                  // staging visible to all waves
    const bool more = (t + 1 < t1);
    if (more) LOAD_KV(t + 1);         // prefetch next tile into regs

    const int kv0 = t * KVBLK;

    // ---- per-32k subtile: QK^T -> mask -> online softmax -> PV ----
    #pragma unroll
    for (int kt = 0; kt < 2; ++kt) {
      // S^T = mfma(A=K, B=Q): col=lane&31=q, row=k
      f32x16 sv;
      __builtin_amdgcn_s_setprio(1);
      {
        f32x16 a;
        #pragma unroll
        for (int i = 0; i < 16; ++i) a[i] = 0.f;
        #pragma unroll
        for (int dc = 0; dc < 4; ++dc) {
          const int nr = 32 * kt + ql;
          const s16x8 kf = *(const s16x8*)((char*)&Ksh[0] + nr * 128 +
                                           ((32 * dc + 16 * hi) ^ FK(nr)));
          a = __builtin_amdgcn_mfma_f32_32x32x16_bf16(kf, qf[dc], a, 0, 0, 0);
        }
        sv = a;
      }
      __builtin_amdgcn_s_setprio(0);

      const int kvt = kv0 + 32 * kt;
      // padding (rare path)
      if (anyPadSh) {
        #pragma unroll
        for (int r1 = 0; r1 < 4; ++r1) {
          const unsigned pd =
              *(const unsigned*)(PadB + kvt + 8 * r1 + 4 * hi);
          #pragma unroll
          for (int r0 = 0; r0 < 4; ++r0)
            if ((pd >> (8 * r0)) & 0xFFu) sv[4 * r1 + r0] = -1e30f;
        }
      }
      // causal mask (diagonal band only): k = kvt+8r1+4hi+r0
      if (kvt + 31 > qw0) {
        #pragma unroll
        for (int r1 = 0; r1 < 4; ++r1)
          #pragma unroll
          for (int r0 = 0; r0 < 4; ++r0)
            if (kvt + 8 * r1 + 4 * hi + r0 > qa) sv[4 * r1 + r0] = -1e30f;
      }

      // online softmax step (tree max, 4-way sum)
      f32x4 m4;
      #pragma unroll
      for (int i = 0; i < 4; ++i)
        m4[i] = fmaxf(fmaxf(sv[i], sv[i + 4]), fmaxf(sv[i + 8], sv[i + 12]));
      float vm = fmaxf(fmaxf(m4[0], m4[1]), fmaxf(m4[2], m4[3]));
      vm = fmaxf(vm, __shfl_xor(vm, 32));         // merge across hi halves
      const float mn   = fmaxf(mrow, vm);
      const float corr = __expf(mrow - mn);
      mrow = mn;
      lrow *= corr;
      #pragma unroll
      for (int dt = 0; dt < 2; ++dt)
        #pragma unroll
        for (int i = 0; i < 16; ++i) acc[dt][i] *= corr;

      float rs0 = 0.f, rs1 = 0.f, rs2 = 0.f, rs3 = 0.f;
      #pragma unroll
      for (int i4 = 0; i4 < 16; i4 += 4) {
        const float p0 = __expf(sv[i4 + 0] - mn);
        const float p1 = __expf(sv[i4 + 1] - mn);
        const float p2 = __expf(sv[i4 + 2] - mn);
        const float p3 = __expf(sv[i4 + 3] - mn);
        sv[i4 + 0] = p0; sv[i4 + 1] = p1;
        sv[i4 + 2] = p2; sv[i4 + 3] = p3;
        rs0 += p0; rs1 += p1; rs2 += p2; rs3 += p3;
      }
      lrow += (rs0 + rs1) + (rs2 + rs3);          // own half-sum only

      // O^T += mfma(A=V^T, B=P): P in C/D-native k-order, V^T same map
      __builtin_amdgcn_s_setprio(1);
      #pragma unroll
      for (int sh = 0; sh < 2; ++sh) {
        const int sk = 2 * kt + sh;
        const int rb = 8 * sh;
        union { unsigned uu[4]; s16x8 v; } pb;
        pb.uu[0] = pk2(sv[rb + 0], sv[rb + 1]);
        pb.uu[1] = pk2(sv[rb + 2], sv[rb + 3]);
        pb.uu[2] = pk2(sv[rb + 4], sv[rb + 5]);
        pb.uu[3] = pk2(sv[rb + 6], sv[rb + 7]);
        #pragma unroll
        for (int dt = 0; dt < 2; ++dt) {
          const int dr = 32 * dt + ql;
          const char* vrow = (char*)&Vtsh[0] + dr * 128;
          const s16x4 v0 = *(const s16x4*)(vrow + ((32 * sk + 8 * hi) ^ FV(dr)));
          const s16x4 v1 = *(const s16x4*)(vrow + ((32 * sk + 16 + 8 * hi) ^ FV(dr)));
          s16x8 vf;
          vf[0] = v0[0]; vf[1] = v0[1]; vf[2] = v0[2]; vf[3] = v0[3];
          vf[4] = v1[0]; vf[5] = v1[1]; vf[6] = v1[2]; vf[7] = v1[3];
          acc[dt] = __builtin_amdgcn_mfma_f32_32x32x16_bf16(vf, pb.v, acc[dt], 0, 0, 0);
        }
      }
      __builtin_amdgcn_s_setprio(0);
    }

    __syncthreads();                  // all waves done reading before restage
  }

  // ---- epilogue: merge l across hi halves; write bf16 partial slot ----
  const float lt = lrow + __shfl_xor(lrow, 32);

  char* slot = Ws + ((size_t)b * TOTC + u) * SLOT_B;
  const int row = 32 * w + ql;
  #pragma unroll
  for (int dt = 0; dt < 2; ++dt)
    #pragma unroll
    for (int r1 = 0; r1 < 4; ++r1) {
      u32x2 p;
      p[0] = pk2(acc[dt][4 * r1 + 0], acc[dt][4 * r1 + 1]);
      p[1] = pk2(acc[dt][4 * r1 + 2], acc[dt][4 * r1 + 3]);
      *(u32x2*)(slot + row * 128 + (32 * dt + 8 * r1 + 4 * hi) * 2) = p;
    }
  if (hi == 0) {
    ((float*)(slot + 16384))[row]       = mrow;
    ((float*)(slot + 16384 + 512))[row] = lt;
  }
}

__global__ __launch_bounds__(256, 8) void fattn_merge(
    const char* __restrict__ Ws, float* __restrict__ Og, int CL, int TOTC)
{
  const int blk = blockIdx.x;            // 512 = 128 qb * 4 quarters
  const int qbi = blk >> 2;
  const int qr  = blk & 3;
  const int Qb  = qbi & (NQB - 1);
  const int b   = qbi >> 5;
  const int tid = threadIdx.x;
  const int row = 32 * qr + (tid >> 3);  // q row within 128-block
  const int d0  = (tid & 7) * 8;         // 8 d-elems per thread

  const int ntt    = 2 * Qb + 2;
  const int nvalid = (ntt + CL - 1) / CL;
  int pre = 0;
  for (int q = 0; q < Qb; ++q) pre += (2 * q + 2 + CL - 1) / CL;

  const char* base = Ws + ((size_t)b * TOTC + pre) * SLOT_B;

  float mstar = -INFINITY;
  for (int ci = 0; ci < nvalid; ++ci)
    mstar = fmaxf(mstar, ((const float*)(base + (size_t)ci * SLOT_B + 16384))[row]);

  float lsum = 0.f;
  float o[8];
  #pragma unroll
  for (int k = 0; k < 8; ++k) o[k] = 0.f;

  for (int ci = 0; ci < nvalid; ++ci) {
    const char* slot = base + (size_t)ci * SLOT_B;
    const float wgt = __expf(((const float*)(slot + 16384))[row] - mstar);
    lsum += wgt * ((const float*)(slot + 16384 + 512))[row];
    const s16x8 ov = *(const s16x8*)(slot + row * 128 + d0 * 2);
    #pragma unroll
    for (int k = 0; k < 8; ++k) o[k] += wgt * bf2f(ov[k]);
  }

  const float inv = 1.0f / lsum;
  float* op = Og + ((size_t)(b * S_LEN + Qb * QBLK + row)) * D_DIM + d0;
  f32x4 o0, o1;
  #pragma unroll
  for (int k = 0; k < 4; ++k) { o0[k] = o[k] * inv; o1[k] = o[4 + k] * inv; }
  *(f32x4*)(op) = o0;
  *(f32x4*)(op + 4) = o1;
}

extern "C" void kernel_launch(void* const* d_in, const int* in_sizes, int n_in,
                              void* d_out, int out_size, void* d_ws, size_t ws_size,
                              hipStream_t stream) {
  const float* Q = (const float*)d_in[0];
  const float* K = (const float*)d_in[1];
  const float* V = (const float*)d_in[2];
  const unsigned char* P = (const unsigned char*)d_in[3];
  float* O  = (float*)d_out;
  char*  Ws = (char*)d_ws;

  // chunk length CL=4 if the slot pool fits, else 8
  int CL = 4;
  int TOTC = 0;
  for (int q = 0; q < NQB; ++q) TOTC += (2 * q + 2 + CL - 1) / CL;   // 272
  if (ws_size < (size_t)NBATCH * TOTC * SLOT_B) {
    CL = 8;
    TOTC = 0;
    for (int q = 0; q < NQB; ++q) TOTC += (2 * q + 2 + CL - 1) / CL; // 144
  }

  dim3 grid(NBATCH * TOTC);
  dim3 block(256);
  hipLaunchKernelGGL(fattn_partial, grid, block, 0, stream, Q, K, V, P, Ws,
                     CL, TOTC);
  hipLaunchKernelGGL(fattn_merge, dim3(NBATCH * NQB * 4), dim3(256), 0, stream,
                     Ws, O, CL, TOTC);
}

// Round 18
// 53.963 us; speedup vs baseline: 1.6972x; 1.0388x over previous
//
#include <hip/hip_runtime.h>
#include <hip/hip_bf16.h>

// Flash attention fwd, causal + key-padding, B=4 S=4096 D=64, fp32 in/out.
// Round 18: round-17 green base with two latency fixes:
//  (a) both kt QK^T MFMA clusters issued back-to-back BEFORE softmax
//      (T15-lite): sm(kt0)'s ~150cyc VALU chain overlaps QK(kt1) MFMA
//      latency instead of serializing after it. Pure code motion.
//  (b) merge kernel: #pragma unroll 4 on slot loops — the serial dependent
//      slot walk (up to 16 slots at CL=4, ~0.5 block/CU) was ~10us of the
//      56; unrolling puts 4 independent global loads in flight.
// Everything else (layouts, staging, partition, slot format) identical.

#define S_LEN 4096
#define D_DIM 64
#define NBATCH 4
#define QBLK 128
#define KVBLK 64
#define NQB (S_LEN / QBLK)          // 32 q-blocks per batch
#define SLOT_B 17408                // 16K bf16 O + 1K fp32 m/l

typedef __attribute__((ext_vector_type(16))) float f32x16;
typedef __attribute__((ext_vector_type(4))) float f32x4;
typedef __attribute__((ext_vector_type(8))) short s16x8;
typedef __attribute__((ext_vector_type(4))) short s16x4;
typedef __attribute__((ext_vector_type(2))) unsigned int u32x2;

#define FK(n) ((((n) ^ ((n) >> 3)) & 7) << 4)                    // K swizzle
#define FV(d) (((((d) & 7) << 4)) ^ ((((d) >> 3) & 1) << 3))     // V^T swizzle

__device__ __forceinline__ unsigned short f2bfu(float f) {
  return __builtin_bit_cast(unsigned short, __float2bfloat16(f));
}
__device__ __forceinline__ unsigned pk2(float a, float b) {
  return (unsigned)f2bfu(a) | ((unsigned)f2bfu(b) << 16);
}
__device__ __forceinline__ float bf2f(short s) {
  return __builtin_bit_cast(float, ((unsigned)(unsigned short)s) << 16);
}

__global__ __launch_bounds__(256, 3) void fattn_partial(
    const float* __restrict__ Qg, const float* __restrict__ Kg,
    const float* __restrict__ Vg, const unsigned char* __restrict__ Pad,
    char* __restrict__ Ws, int CL, int TOTC)
{
  // Uniform partition: enumeration index u -> (Qb, ci); heavy-first.
  const int wid = blockIdx.x;
  const int b   = wid & 3;
  const int u   = TOTC - 1 - (wid >> 2);
  int Qb = 0, ci = 0;
  {
    int uu = u, q = 0;
    while (true) {
      const int nch = (2 * q + 2 + CL - 1) / CL;
      if (uu < nch) { ci = uu; break; }
      uu -= nch; ++q;
    }
    Qb = q;
  }
  const int q0  = Qb * QBLK;
  const int ntt = 2 * Qb + 2;
  const int t0  = ci * CL;
  const int t1  = (t0 + CL < ntt) ? (t0 + CL) : ntt;

  const int tid = threadIdx.x;
  const int w   = tid >> 6;          // wave 0..3 -> q rows [q0+32w, q0+32w+32)
  const int l   = tid & 63;
  const int ql  = l & 31;
  const int hi  = l >> 5;
  const int qw0 = q0 + 32 * w;
  const int qa  = qw0 + ql;

  // K staging roles (64 rows x 16-float windows over 256 threads)
  const int sq  = l & 3;
  const int sm  = (l >> 2) & 3;
  const int sc2 = l >> 4;
  const int snb = 4 * w + 16 * sc2;  // n-chunk base (multiple of 4)
  // V staging roles: one 4x4 block per thread (in-lane transpose)
  const int vn0 = (tid & 15) << 2;   // V rows [vn0, vn0+4)
  const int vd0 = (tid >> 4) << 2;   // V cols [vd0, vd0+4)

  __shared__ short Ksh[KVBLK * D_DIM];    // [n][d] bf16, FK-swizzled
  __shared__ short Vtsh[D_DIM * KVBLK];   // [d][n] bf16 (V^T), FV-swizzled
  __shared__ int anyPadSh;

  const size_t bS = (size_t)b * S_LEN;
  const unsigned char* PadB = Pad + bS;

  // ---- prologue: block-wide padding flag for this chunk's key range ----
  if (tid == 0) anyPadSh = 0;
  __syncthreads();
  {
    const int nk  = (t1 - t0) * KVBLK;      // <= 512
    const int idx = 2 * tid;
    if (idx < nk) {
      const unsigned char* pp = PadB + t0 * KVBLK + idx;
      const bool nz = pp[0] || ((idx + 1 < nk) ? pp[1] : (unsigned char)0);
      if (nz) anyPadSh = 1;                 // benign same-value race
    }
  }

  // ---- Q fragments (B-operand), pre-scaled by 1/8 ----
  s16x8 qf[4];
  {
    const float* qp = Qg + (bS + qa) * D_DIM + 8 * hi;
    #pragma unroll
    for (int dc = 0; dc < 4; ++dc)
      #pragma unroll
      for (int j = 0; j < 8; ++j)
        qf[dc][j] = (short)f2bfu(qp[16 * dc + j] * 0.125f);
  }

  f32x16 acc[2];
  #pragma unroll
  for (int dt = 0; dt < 2; ++dt)
    #pragma unroll
    for (int i = 0; i < 16; ++i) acc[dt][i] = 0.f;
  float mrow = -INFINITY;
  float lrow = 0.f;

  u32x2 kpb[4], vpb[4];   // bf16-packed prefetch; vpb already transposed

#define LOAD_KV(T) do {                                                      \
    const int kv0_ = (T) * KVBLK;                                            \
    _Pragma("unroll")                                                        \
    for (int s_ = 0; s_ < 4; ++s_) {                                         \
      const size_t go_ =                                                     \
          (bS + kv0_ + snb + sq) * D_DIM + 16 * s_ + 4 * sm;                 \
      const float4 kx = *(const float4*)(Kg + go_);                          \
      kpb[s_][0] = pk2(kx.x, kx.y); kpb[s_][1] = pk2(kx.z, kx.w);            \
    }                                                                        \
    const float* vp_ = Vg + (bS + kv0_ + vn0) * D_DIM + vd0;                 \
    const float4 r0 = *(const float4*)(vp_);                                 \
    const float4 r1 = *(const float4*)(vp_ + D_DIM);                         \
    const float4 r2 = *(const float4*)(vp_ + 2 * D_DIM);                     \
    const float4 r3 = *(const float4*)(vp_ + 3 * D_DIM);                     \
    const float* f0 = (const float*)&r0; const float* f1 = (const float*)&r1;\
    const float* f2 = (const float*)&r2; const float* f3 = (const float*)&r3;\
    _Pragma("unroll")                                                        \
    for (int j_ = 0; j_ < 4; ++j_) {                                         \
      vpb[j_][0] = pk2(f0[j_], f1[j_]);                                      \
      vpb[j_][1] = pk2(f2[j_], f3[j_]);                                      \
    }                                                                        \
  } while (0)

#define STAGE() do {                                                         \
    _Pragma("unroll")                                                        \
    for (int s_ = 0; s_ < 4; ++s_) {                                         \
      const int d0_ = 16 * s_ + 4 * sm; const int nk_ = snb + sq;            \
      *(u32x2*)((char*)&Ksh[0] + nk_ * 128 + ((2 * d0_) ^ FK(nk_))) =        \
          kpb[s_];                                                           \
      const int dv_ = vd0 + s_;                                              \
      *(u32x2*)((char*)&Vtsh[0] + dv_ * 128 + ((2 * vn0) ^ FV(dv_))) =       \
          vpb[s_];                                                           \
    }                                                                        \
  } while (0)

  LOAD_KV(t0);

  for (int t = t0; t < t1; ++t) {
    STAGE();                          // write prefetched tile to LDS
    __syncthreads();                  // staging visible to all waves
    const bool more = (t + 1 < t1);
    if (more) LOAD_KV(t + 1);         // prefetch next tile into regs

    const int kv0 = t * KVBLK;

    // ---- BOTH QK^T clusters first (sm(0) then overlaps QK(1) latency) ----
    f32x16 sv0, sv1;
    __builtin_amdgcn_s_setprio(1);
    {
      f32x16 a;
      #pragma unroll
      for (int i = 0; i < 16; ++i) a[i] = 0.f;
      #pragma unroll
      for (int dc = 0; dc < 4; ++dc) {
        const int nr = ql;
        const s16x8 kf = *(const s16x8*)((char*)&Ksh[0] + nr * 128 +
                                         ((32 * dc + 16 * hi) ^ FK(nr)));
        a = __builtin_amdgcn_mfma_f32_32x32x16_bf16(kf, qf[dc], a, 0, 0, 0);
      }
      sv0 = a;
    }
    {
      f32x16 a;
      #pragma unroll
      for (int i = 0; i < 16; ++i) a[i] = 0.f;
      #pragma unroll
      for (int dc = 0; dc < 4; ++dc) {
        const int nr = 32 + ql;
        const s16x8 kf = *(const s16x8*)((char*)&Ksh[0] + nr * 128 +
                                         ((32 * dc + 16 * hi) ^ FK(nr)));
        a = __builtin_amdgcn_mfma_f32_32x32x16_bf16(kf, qf[dc], a, 0, 0, 0);
      }
      sv1 = a;
    }
    __builtin_amdgcn_s_setprio(0);

    // ---- per-32k subtile: mask -> online softmax -> PV ----
    #pragma unroll
    for (int kt = 0; kt < 2; ++kt) {
      f32x16 sv = (kt == 0) ? sv0 : sv1;
      const int kvt = kv0 + 32 * kt;
      // padding (rare path)
      if (anyPadSh) {
        #pragma unroll
        for (int r1 = 0; r1 < 4; ++r1) {
          const unsigned pd =
              *(const unsigned*)(PadB + kvt + 8 * r1 + 4 * hi);
          #pragma unroll
          for (int r0 = 0; r0 < 4; ++r0)
            if ((pd >> (8 * r0)) & 0xFFu) sv[4 * r1 + r0] = -1e30f;
        }
      }
      // causal mask (diagonal band only): k = kvt+8r1+4hi+r0
      if (kvt + 31 > qw0) {
        #pragma unroll
        for (int r1 = 0; r1 < 4; ++r1)
          #pragma unroll
          for (int r0 = 0; r0 < 4; ++r0)
            if (kvt + 8 * r1 + 4 * hi + r0 > qa) sv[4 * r1 + r0] = -1e30f;
      }

      // online softmax step (tree max, 4-way sum)
      f32x4 m4;
      #pragma unroll
      for (int i = 0; i < 4; ++i)
        m4[i] = fmaxf(fmaxf(sv[i], sv[i + 4]), fmaxf(sv[i + 8], sv[i + 12]));
      float vm = fmaxf(fmaxf(m4[0], m4[1]), fmaxf(m4[2], m4[3]));
      vm = fmaxf(vm, __shfl_xor(vm, 32));         // merge across hi halves
      const float mn   = fmaxf(mrow, vm);
      const float corr = __expf(mrow - mn);
      mrow = mn;
      lrow *= corr;
      #pragma unroll
      for (int dt = 0; dt < 2; ++dt)
        #pragma unroll
        for (int i = 0; i < 16; ++i) acc[dt][i] *= corr;

      float rs0 = 0.f, rs1 = 0.f, rs2 = 0.f, rs3 = 0.f;
      #pragma unroll
      for (int i4 = 0; i4 < 16; i4 += 4) {
        const float p0 = __expf(sv[i4 + 0] - mn);
        const float p1 = __expf(sv[i4 + 1] - mn);
        const float p2 = __expf(sv[i4 + 2] - mn);
        const float p3 = __expf(sv[i4 + 3] - mn);
        sv[i4 + 0] = p0; sv[i4 + 1] = p1;
        sv[i4 + 2] = p2; sv[i4 + 3] = p3;
        rs0 += p0; rs1 += p1; rs2 += p2; rs3 += p3;
      }
      lrow += (rs0 + rs1) + (rs2 + rs3);          // own half-sum only

      // O^T += mfma(A=V^T, B=P): P in C/D-native k-order, V^T same map
      __builtin_amdgcn_s_setprio(1);
      #pragma unroll
      for (int sh = 0; sh < 2; ++sh) {
        const int sk = 2 * kt + sh;
        const int rb = 8 * sh;
        union { unsigned uu[4]; s16x8 v; } pb;
        pb.uu[0] = pk2(sv[rb + 0], sv[rb + 1]);
        pb.uu[1] = pk2(sv[rb + 2], sv[rb + 3]);
        pb.uu[2] = pk2(sv[rb + 4], sv[rb + 5]);
        pb.uu[3] = pk2(sv[rb + 6], sv[rb + 7]);
        #pragma unroll
        for (int dt = 0; dt < 2; ++dt) {
          const int dr = 32 * dt + ql;
          const char* vrow = (char*)&Vtsh[0] + dr * 128;
          const s16x4 v0 = *(const s16x4*)(vrow + ((32 * sk + 8 * hi) ^ FV(dr)));
          const s16x4 v1 = *(const s16x4*)(vrow + ((32 * sk + 16 + 8 * hi) ^ FV(dr)));
          s16x8 vf;
          vf[0] = v0[0]; vf[1] = v0[1]; vf[2] = v0[2]; vf[3] = v0[3];
          vf[4] = v1[0]; vf[5] = v1[1]; vf[6] = v1[2]; vf[7] = v1[3];
          acc[dt] = __builtin_amdgcn_mfma_f32_32x32x16_bf16(vf, pb.v, acc[dt], 0, 0, 0);
        }
      }
      __builtin_amdgcn_s_setprio(0);
    }

    __syncthreads();                  // all waves done reading before restage
  }

  // ---- epilogue: merge l across hi halves; write bf16 partial slot ----
  const float lt = lrow + __shfl_xor(lrow, 32);

  char* slot = Ws + ((size_t)b * TOTC + u) * SLOT_B;
  const int row = 32 * w + ql;
  #pragma unroll
  for (int dt = 0; dt < 2; ++dt)
    #pragma unroll
    for (int r1 = 0; r1 < 4; ++r1) {
      u32x2 p;
      p[0] = pk2(acc[dt][4 * r1 + 0], acc[dt][4 * r1 + 1]);
      p[1] = pk2(acc[dt][4 * r1 + 2], acc[dt][4 * r1 + 3]);
      *(u32x2*)(slot + row * 128 + (32 * dt + 8 * r1 + 4 * hi) * 2) = p;
    }
  if (hi == 0) {
    ((float*)(slot + 16384))[row]       = mrow;
    ((float*)(slot + 16384 + 512))[row] = lt;
  }
}

__global__ __launch_bounds__(256, 8) void fattn_merge(
    const char* __restrict__ Ws, float* __restrict__ Og, int CL, int TOTC)
{
  const int blk = blockIdx.x;            // 512 = 128 qb * 4 quarters
  const int qbi = blk >> 2;
  const int qr  = blk & 3;
  const int Qb  = qbi & (NQB - 1);
  const int b   = qbi >> 5;
  const int tid = threadIdx.x;
  const int row = 32 * qr + (tid >> 3);  // q row within 128-block
  const int d0  = (tid & 7) * 8;         // 8 d-elems per thread

  const int ntt    = 2 * Qb + 2;
  const int nvalid = (ntt + CL - 1) / CL;
  int pre = 0;
  for (int q = 0; q < Qb; ++q) pre += (2 * q + 2 + CL - 1) / CL;

  const char* base = Ws + ((size_t)b * TOTC + pre) * SLOT_B;

  float mstar = -INFINITY;
  #pragma unroll 4
  for (int ci = 0; ci < nvalid; ++ci)
    mstar = fmaxf(mstar, ((const float*)(base + (size_t)ci * SLOT_B + 16384))[row]);

  float lsum = 0.f;
  float o[8];
  #pragma unroll
  for (int k = 0; k < 8; ++k) o[k] = 0.f;

  #pragma unroll 4
  for (int ci = 0; ci < nvalid; ++ci) {
    const char* slot = base + (size_t)ci * SLOT_B;
    const float wgt = __expf(((const float*)(slot + 16384))[row] - mstar);
    lsum += wgt * ((const float*)(slot + 16384 + 512))[row];
    const s16x8 ov = *(const s16x8*)(slot + row * 128 + d0 * 2);
    #pragma unroll
    for (int k = 0; k < 8; ++k) o[k] += wgt * bf2f(ov[k]);
  }

  const float inv = 1.0f / lsum;
  float* op = Og + ((size_t)(b * S_LEN + Qb * QBLK + row)) * D_DIM + d0;
  f32x4 o0, o1;
  #pragma unroll
  for (int k = 0; k < 4; ++k) { o0[k] = o[k] * inv; o1[k] = o[4 + k] * inv; }
  *(f32x4*)(op) = o0;
  *(f32x4*)(op + 4) = o1;
}

extern "C" void kernel_launch(void* const* d_in, const int* in_sizes, int n_in,
                              void* d_out, int out_size, void* d_ws, size_t ws_size,
                              hipStream_t stream) {
  const float* Q = (const float*)d_in[0];
  const float* K = (const float*)d_in[1];
  const float* V = (const float*)d_in[2];
  const unsigned char* P = (const unsigned char*)d_in[3];
  float* O  = (float*)d_out;
  char*  Ws = (char*)d_ws;

  // chunk length CL=4 if the slot pool fits, else 8
  int CL = 4;
  int TOTC = 0;
  for (int q = 0; q < NQB; ++q) TOTC += (2 * q + 2 + CL - 1) / CL;   // 272
  if (ws_size < (size_t)NBATCH * TOTC * SLOT_B) {
    CL = 8;
    TOTC = 0;
    for (int q = 0; q < NQB; ++q) TOTC += (2 * q + 2 + CL - 1) / CL; // 144
  }

  dim3 grid(NBATCH * TOTC);
  dim3 block(256);
  hipLaunchKernelGGL(fattn_partial, grid, block, 0, stream, Q, K, V, P, Ws,
                     CL, TOTC);
  hipLaunchKernelGGL(fattn_merge, dim3(NBATCH * NQB * 4), dim3(256), 0, stream,
                     Ws, O, CL, TOTC);
}